// Round 14
// baseline (297.693 us; speedup 1.0000x reference)
//
#include <hip/hip_runtime.h>
#include <math.h>

// Min-sum BP LDPC decoder, LDS-resident messages, degree-sorted checks.
// One block = one batch element; padded msg arena (~160 KB) lives in LDS.
//
// R15 = R14 (two dispatches, 297.4 total / 127.5 bp: stride ≡ 2 mod 4 + b64
// check LDS + iter-0 peel + xor-sign + exact-degree dispatch + big-fallback
// for d<=3/13+, ZERO spills: WRITE_SIZE == outputs exactly) + 2-VAR BATCHED
// VAR PHASE:
//  - R14 counters: VALU 31%, LDS ~48%, occupancy 45% -> latency-bound.
//    The var k-loop reads/writes msg[] via runtime addresses; the compiler
//    cannot prove var k+1's reads disjoint from var k's writes and
//    serializes 8 LDS round-trips per thread per iter. The slots ARE
//    disjoint (each edge belongs to exactly one var).
//  - Batch 2 vars: issue all 8 reads (reads never alias reads), then
//    compute+write both. Chain depth 8 -> 4. Extra live state = 4 floats
//    (~62 VGPR est., under the 64-VGPR allocator pin). R9's 32-value batch
//    spilled; 2-var is the largest batch that fits.
//  - Values, operand order, sum order BYTE-IDENTICAL — pure scheduling.
//  - Tripwire: WRITE_SIZE must stay 16392 KB / FETCH ~8.3 MB; any growth
//    = spill = revert to R14.
//  - HARD CONSTRAINTS: 64-VGPR pin (R3/R9/R14); never reorder reference FP
//    math (R6); 2 dispatches minimum (R7/R8/R13).

#define BLOCK 1024
#define NV    8192          // N variables
#define MC    4096          // M checks
#define NE    32768         // E edges (N * DV, DV=4)
#define VPT   (NV / BLOCK)  // 8 vars per thread
#define CPT   (MC / BLOCK)  // 4 checks per thread
#define NITER 10
#define ALPHA 0.8f
#define CLAMP 20.0f
#define MSGW  40896         // padded arena words (159.9 KB)
#define SGNB  0x80000000

// ws layout (ints), 32 KB:
//  [0 .. MC)   : pbase(16b) | deg<<16   (degree-sorted order)
//  [MC .. 2MC) : original check index   (for syndrome + check_adj lookup)

// stride: smallest s >= d with s ≡ 2 (mod 4)  [even base for b64 + banking]
__device__ __forceinline__ int pad_stride(int d) { return d + ((2 - (d & 3)) & 3); }

// ---------------- setup: counting-sort + padded prefix (proven) ----------------
__global__ __launch_bounds__(BLOCK)
void setup_sort(const float* __restrict__ check_mask,
                const int*   __restrict__ check_adj,
                int max_dc, int* __restrict__ ws)
{
    __shared__ int hist[64], cbase[64], wsum[16];
    __shared__ int sdeg[MC];
    const int t = threadIdx.x;
    if (t < 64) hist[t] = 0;
    __syncthreads();
    int deg[CPT];
#pragma unroll
    for (int k = 0; k < CPT; ++k) {
        const int c = t + k * BLOCK;
        int d = 0;
        for (int j = 0; j < max_dc; ++j)
            d += (check_mask[(size_t)c * max_dc + j] != 0.0f) ? 1 : 0;
        deg[k] = d;
        atomicAdd(&hist[d & 63], 1);
    }
    __syncthreads();
    if (t == 0) {
        int s = 0;
        for (int i = 0; i < 64; ++i) { cbase[i] = s; s += hist[i]; }
    }
    __syncthreads();
#pragma unroll
    for (int k = 0; k < CPT; ++k) {
        const int pos = atomicAdd(&cbase[deg[k] & 63], 1);
        sdeg[pos]    = deg[k];
        ws[MC + pos] = t + k * BLOCK;
    }
    __syncthreads();
    int psz[CPT];
    int s = 0;
#pragma unroll
    for (int k = 0; k < CPT; ++k) {
        const int d = sdeg[4 * t + k];
        psz[k] = s;
        s += pad_stride(d);             // even, ≡2 mod 4
    }
    const int lane = t & 63, wv = t >> 6;
    int run = s;
#pragma unroll
    for (int off = 1; off < 64; off <<= 1) {
        const int n = __shfl_up(run, off, 64);
        if (lane >= off) run += n;
    }
    if (lane == 63) wsum[wv] = run;
    __syncthreads();
    if (t == 0) {
        int acc = 0;
        for (int w = 0; w < 16; ++w) { const int v = wsum[w]; wsum[w] = acc; acc += v; }
    }
    __syncthreads();
    const int tb = wsum[wv] + (run - s);
#pragma unroll
    for (int k = 0; k < CPT; ++k) {
        const int i = 4 * t + k;
        ws[i] = ((tb + psz[k]) & 0xFFFF) | (sdeg[i] << 16);
    }
}

// Exact-degree check update, b64 vectorized, byte-base addressing.
// ssb = syndrome sign bit (bit31). Bit-exact vs reference (validated R9-R14).
template<int D>
__device__ __forceinline__ void do_check_x(char* __restrict__ mb,
                                           int stB, int ssb, float pad)
{
    float x[D];
    constexpr int P = D / 2;
#pragma unroll
    for (int p = 0; p < P; ++p) {
        const float2 r = *(const float2*)(mb + stB + 8 * p);
        x[2 * p]     = r.x;
        x[2 * p + 1] = r.y;
    }
    if constexpr (D & 1)
        x[D - 1] = *(const float*)(mb + stB + 4 * (D - 1));

    float min1 = pad, min2 = pad;
    int sb = ssb;
#pragma unroll
    for (int j = 0; j < D; ++j) {
        sb ^= __float_as_int(x[j]);                     // sign parity (no -0.0)
        const float a = fabsf(x[j]);
        min2 = __builtin_amdgcn_fmed3f(min1, min2, a);  // uses OLD min1
        min1 = fminf(min1, a);
    }
    const float vm1 = ALPHA * min1;
    const float vm2 = ALPHA * min2;
#pragma unroll
    for (int p = 0; p < P; ++p) {
        const int j0 = 2 * p, j1 = 2 * p + 1;
        const float m0 = (fabsf(fabsf(x[j0]) - min1) < 1e-9f) ? vm2 : vm1;  // REF tie rule
        const float m1 = (fabsf(fabsf(x[j1]) - min1) < 1e-9f) ? vm2 : vm1;
        float2 w;
        w.x = __int_as_float(__float_as_int(m0) | ((sb ^ __float_as_int(x[j0])) & SGNB));
        w.y = __int_as_float(__float_as_int(m1) | ((sb ^ __float_as_int(x[j1])) & SGNB));
        *(float2*)(mb + stB + 8 * p) = w;
    }
    if constexpr (D & 1) {
        const int jt = D - 1;
        const float mt = (fabsf(fabsf(x[jt]) - min1) < 1e-9f) ? vm2 : vm1;
        *(float*)(mb + stB + 4 * jt) =
            __int_as_float(__float_as_int(mt) | ((sb ^ __float_as_int(x[jt])) & SGNB));
    }
}

// Generic fallback (LDS re-read, no register cache): d<=3, 13..16, >16, d==0.
__device__ void do_check_big(char* __restrict__ mb,
                             int stB, int d, int ssb, float pad)
{
    float min1 = pad, min2 = pad;
    int sb = ssb;
    for (int j = 0; j < d; ++j) {
        const float xx = *(const float*)(mb + stB + 4 * j);
        sb ^= __float_as_int(xx);
        const float aa = fabsf(xx);
        min2 = __builtin_amdgcn_fmed3f(min1, min2, aa);
        min1 = fminf(min1, aa);
    }
    const float vm1 = ALPHA * min1;
    const float vm2 = ALPHA * min2;
    for (int j = 0; j < d; ++j) {
        const float xx = *(const float*)(mb + stB + 4 * j);
        const float m  = (fabsf(fabsf(xx) - min1) < 1e-9f) ? vm2 : vm1;
        *(float*)(mb + stB + 4 * j) =
            __int_as_float(__float_as_int(m) | ((sb ^ __float_as_int(xx)) & SGNB));
    }
}

// Check phase for one k-step: exact-degree tree (wave-coherent after sort).
__device__ __forceinline__ void check_dispatch(char* __restrict__ mb,
                                               int stB, int d, int ssb, float pad)
{
    if      (d == 8)  do_check_x<8>(mb, stB, ssb, pad);
    else if (d == 7)  do_check_x<7>(mb, stB, ssb, pad);
    else if (d == 9)  do_check_x<9>(mb, stB, ssb, pad);
    else if (d == 6)  do_check_x<6>(mb, stB, ssb, pad);
    else if (d == 10) do_check_x<10>(mb, stB, ssb, pad);
    else if (d == 5)  do_check_x<5>(mb, stB, ssb, pad);
    else if (d == 11) do_check_x<11>(mb, stB, ssb, pad);
    else if (d == 12) do_check_x<12>(mb, stB, ssb, pad);
    else if (d == 4)  do_check_x<4>(mb, stB, ssb, pad);
    else              do_check_big(mb, stB, d, ssb, pad);   // d<=3, 13.., 0
}

__global__ __launch_bounds__(BLOCK) __attribute__((amdgpu_waves_per_eu(4, 4)))
void bp_decode(const float* __restrict__ syndrome,    // (B, M)
               const float* __restrict__ llr_g,       // (B, N)
               const int*   __restrict__ var_adj,     // (N, 4)
               const int*   __restrict__ var_idx,     // (E,)
               const int*   __restrict__ check_adj,   // (M, max_dc)
               int max_dc,
               const int*   __restrict__ ws,          // sorted check info
               float* __restrict__ out,               // marginals | hard | converged
               int B)
{
    __shared__ float msg[MSGW];  // padded arena, in-place ctv/vtc
    __shared__ float sh_e0;      // |vtc[edge 0]| snapshot for reference's pad
    __shared__ int   mism;

    const int b = blockIdx.x;
    const int t = threadIdx.x;
    char* mb = (char*)msg;

    // ---- load sorted-check info; build pos[e] in LDS (aliasing msg) ----
    int cstB[CPT], dsb[CPT];   // byte base; (deg<<1) | syndrome_bit
    {
        int* posL = (int*)msg;
#pragma unroll
        for (int k = 0; k < CPT; ++k) {
            const int i = t + k * BLOCK;
            const int w = ws[i];
            const int c = ws[MC + i];
            const int pb = w & 0xFFFF;
            const int d  = w >> 16;
            cstB[k] = pb << 2;
            const int sb = (syndrome[(size_t)b * MC + c] > 0.5f) ? 1 : 0;
            dsb[k] = (d << 1) | sb;
            const int st = check_adj[(size_t)c * max_dc];  // first edge (contiguous)
            for (int j = 0; j < d; ++j)
                posL[st + j] = pb + j;
        }
    }
    __syncthreads();

    // ---- edge-0 owner info (reference's pad = |vtc[0]| + 1e6) ----
    const int  v0  = var_idx[0];
    const bool own = (t == (v0 & (BLOCK - 1)));      // thread that writes edge 0
    const int  e0B = ((const int*)msg)[0] << 2;      // posL[0] as byte offset

    // ---- var-side padded slots (byte offsets) + LLRs into registers ----
    int   vsB[VPT][4];
    float llr[VPT];
    {
        const int* posL = (const int*)msg;
#pragma unroll
        for (int k = 0; k < VPT; ++k) {
            const int v = t + k * BLOCK;
            const int4 a = ((const int4*)var_adj)[v];   // var degree is exactly 4
            vsB[k][0] = posL[a.x] << 2; vsB[k][1] = posL[a.y] << 2;
            vsB[k][2] = posL[a.z] << 2; vsB[k][3] = posL[a.w] << 2;
            llr[k] = llr_g[(size_t)b * NV + v];
        }
    }
    __syncthreads();   // posL reads done; msg may now be overwritten (no zero-fill:
                       // iter 0 writes every edge slot; pad gaps are never read)

    // ======== iter 0 (peeled): ctv==0 -> vtc = clip(llr), write-only ========
#pragma unroll
    for (int k = 0; k < VPT; ++k) {
        const float o = __builtin_amdgcn_fmed3f(llr[k], -CLAMP, CLAMP);
        *(float*)(mb + vsB[k][0]) = o;
        *(float*)(mb + vsB[k][1]) = o;
        *(float*)(mb + vsB[k][2]) = o;
        *(float*)(mb + vsB[k][3]) = o;
    }
    if (own) sh_e0 = fabsf(*(const float*)(mb + e0B)) + 1.0e6f;  // own write, RAW-ordered
    __syncthreads();
    {
        const float pad = sh_e0;
#pragma unroll
        for (int k = 0; k < CPT; ++k)
            check_dispatch(mb, cstB[k], dsb[k] >> 1, (dsb[k] & 1) << 31, pad);
    }
    __syncthreads();

    // ======== iters 1..NITER-1 ========
#pragma unroll 1
    for (int it = 1; it < NITER; ++it) {
        // ---- variable phase, 2-var batches: all 8 reads issue before any
        //      write (reads never alias reads); slots are thread-disjoint so
        //      values are identical to the serial order. Chain depth 8 -> 4.
#pragma unroll
        for (int k = 0; k < VPT; k += 2) {
            const float a0 = *(const float*)(mb + vsB[k][0]);
            const float a1 = *(const float*)(mb + vsB[k][1]);
            const float a2 = *(const float*)(mb + vsB[k][2]);
            const float a3 = *(const float*)(mb + vsB[k][3]);
            const float b0 = *(const float*)(mb + vsB[k + 1][0]);
            const float b1 = *(const float*)(mb + vsB[k + 1][1]);
            const float b2 = *(const float*)(mb + vsB[k + 1][2]);
            const float b3 = *(const float*)(mb + vsB[k + 1][3]);

            const float totA = ((a0 + a1) + a2) + a3;   // reference sum order
            const float bseA = llr[k] + totA;
            *(float*)(mb + vsB[k][0]) = __builtin_amdgcn_fmed3f(bseA - a0, -CLAMP, CLAMP);
            *(float*)(mb + vsB[k][1]) = __builtin_amdgcn_fmed3f(bseA - a1, -CLAMP, CLAMP);
            *(float*)(mb + vsB[k][2]) = __builtin_amdgcn_fmed3f(bseA - a2, -CLAMP, CLAMP);
            *(float*)(mb + vsB[k][3]) = __builtin_amdgcn_fmed3f(bseA - a3, -CLAMP, CLAMP);

            const float totB = ((b0 + b1) + b2) + b3;
            const float bseB = llr[k + 1] + totB;
            *(float*)(mb + vsB[k + 1][0]) = __builtin_amdgcn_fmed3f(bseB - b0, -CLAMP, CLAMP);
            *(float*)(mb + vsB[k + 1][1]) = __builtin_amdgcn_fmed3f(bseB - b1, -CLAMP, CLAMP);
            *(float*)(mb + vsB[k + 1][2]) = __builtin_amdgcn_fmed3f(bseB - b2, -CLAMP, CLAMP);
            *(float*)(mb + vsB[k + 1][3]) = __builtin_amdgcn_fmed3f(bseB - b3, -CLAMP, CLAMP);
        }
        if (own) sh_e0 = fabsf(*(const float*)(mb + e0B)) + 1.0e6f;   // own write, ordered
        __syncthreads();
        const float pad = sh_e0;

        // ---- check phase: contiguous padded regions, b64 pairs ----
#pragma unroll
        for (int k = 0; k < CPT; ++k)
            check_dispatch(mb, cstB[k], dsb[k] >> 1, (dsb[k] & 1) << 31, pad);
        __syncthreads();
    }

    // ---- finale: marginals, hard decisions, convergence ----
    float marg[VPT], hard[VPT];
#pragma unroll
    for (int k = 0; k < VPT; ++k) {
        const float c0 = *(const float*)(mb + vsB[k][0]);
        const float c1 = *(const float*)(mb + vsB[k][1]);
        const float c2 = *(const float*)(mb + vsB[k][2]);
        const float c3 = *(const float*)(mb + vsB[k][3]);
        const float tot = ((c0 + c1) + c2) + c3;
        const float tl  = llr[k] + tot;
        const float mg  = 1.0f / (1.0f + expf(tl));   // sigmoid(-tl)
        marg[k] = mg;
        hard[k] = (mg > 0.5f) ? 1.0f : 0.0f;
    }
    if (t == 0) mism = 0;
    __syncthreads();   // all ctv reads done; safe to overwrite msg

    const size_t BN = (size_t)B * NV;
#pragma unroll
    for (int k = 0; k < VPT; ++k) {
        const int v = t + k * BLOCK;
        out[(size_t)b * NV + v]      = marg[k];        // output 0: marginals
        out[BN + (size_t)b * NV + v] = hard[k];        // output 1: hard_decision
        const float h = hard[k];                       // scatter hard bit to edges
        *(float*)(mb + vsB[k][0]) = h;
        *(float*)(mb + vsB[k][1]) = h;
        *(float*)(mb + vsB[k][2]) = h;
        *(float*)(mb + vsB[k][3]) = h;
    }
    __syncthreads();

    // syn_hat[c] = parity over the check's edges' hard bits; converged iff == syndrome
#pragma unroll
    for (int k = 0; k < CPT; ++k) {
        const int d  = dsb[k] >> 1;
        const int sb = dsb[k] & 1;
        int par = 0;
        for (int j = 0; j < d; ++j)
            par ^= (*(const float*)(mb + cstB[k] + 4 * j) != 0.0f) ? 1 : 0;
        if (par != sb) mism = 1;   // benign race: all writers store 1
    }
    __syncthreads();
    if (t == 0) out[2 * BN + b] = mism ? 0.0f : 1.0f;  // output 2: converged
}

extern "C" void kernel_launch(void* const* d_in, const int* in_sizes, int n_in,
                              void* d_out, int out_size, void* d_ws, size_t ws_size,
                              hipStream_t stream) {
    const float* syndrome   = (const float*)d_in[0];
    const float* llr        = (const float*)d_in[1];
    const int*   var_adj    = (const int*)d_in[2];
    // d_in[3] var_adj_mask: all ones (DV=4 exact) — unused
    const int*   check_adj  = (const int*)d_in[4];
    const float* check_mask = (const float*)d_in[5];
    const int*   var_idx    = (const int*)d_in[6];
    // d_in[7] pcm_dense — unused
    float* out = (float*)d_out;
    int*   ws  = (int*)d_ws;    // needs 2*MC ints = 32 KB (proven size)

    const int B      = in_sizes[0] / MC;      // 256
    const int max_dc = in_sizes[4] / MC;

    setup_sort<<<1, BLOCK, 0, stream>>>(check_mask, check_adj, max_dc, ws);
    bp_decode<<<B, BLOCK, 0, stream>>>(syndrome, llr, var_adj, var_idx,
                                       check_adj, max_dc, ws, out, B);
}